// Round 1
// 376.270 us; speedup vs baseline: 1.0052x; 1.0052x over previous
//
#include <hip/hip_runtime.h>
#include <hip/hip_bf16.h>
#include <math.h>

#define N_TOK 8192
#define DDIM  1024
#define HDIM  4096
#define NBLK  512

typedef __bf16 bf16x8 __attribute__((ext_vector_type(8)));
typedef __bf16 bf16x4 __attribute__((ext_vector_type(4)));
typedef float  floatx4 __attribute__((ext_vector_type(4)));

__device__ __forceinline__ float wave_reduce_sum(float v) {
#pragma unroll
    for (int off = 32; off > 0; off >>= 1) v += __shfl_down(v, off, 64);
    return v;
}

__device__ __forceinline__ void gload_lds16(const void* g, void* l) {
    __builtin_amdgcn_global_load_lds((const __attribute__((address_space(1))) void*)g,
                                     (__attribute__((address_space(3))) void*)l,
                                     16, 0, 0);
}

// Branchless gelu via A&S 7.1.26 erf (max err 1.5e-7), ~13 VALU ops.
__device__ __forceinline__ float fast_gelu(float x) {
    float ax = fabsf(x);
    float z  = ax * 0.70710678118654752f;
    float t  = __builtin_amdgcn_rcpf(fmaf(0.3275911f, z, 1.0f));
    float p  = fmaf(fmaf(fmaf(fmaf(1.061405429f, t, -1.453152027f),
                              t, 1.421413741f),
                         t, -0.284496736f),
                    t, 0.254829592f);
    p *= t;
    float e = __expf(-z * z);
    float E = fmaf(-p, e, 1.0f);
    return 0.5f * fmaf(ax, E, x);
}

__device__ __forceinline__ float fast_softplus(float r) {
    return __logf(fmaf(1.0f, __expf(r), 1.0f));
}

// ---------------------------------------------------------------------------
// Fused prep kernel: unit rows / LN+x-cast / W casts
// ---------------------------------------------------------------------------
__device__ __forceinline__ void cast1024(const float* __restrict__ s,
                                         __bf16* __restrict__ d,
                                         size_t off, int t) {
    float4 v = ((const float4*)(s + off))[t];
    bf16x4 o;
    o.x = (__bf16)v.x; o.y = (__bf16)v.y;
    o.z = (__bf16)v.z; o.w = (__bf16)v.w;
    ((bf16x4*)(d + off))[t] = o;
}

__global__ __launch_bounds__(256) void prep_kernel(
        const float* __restrict__ x,
        const float* __restrict__ ln_g, const float* __restrict__ ln_b,
        const float* __restrict__ W1,   const float* __restrict__ W2,
        const float* __restrict__ router_W,
        const float* __restrict__ rawU, const float* __restrict__ rawV,
        __bf16* __restrict__ xb,  __bf16* __restrict__ lnb,
        __bf16* __restrict__ w1b, __bf16* __restrict__ w2b,
        __bf16* __restrict__ rwb,
        float* __restrict__ unitU, float* __restrict__ unitV) {
    int b = blockIdx.x;
    int t = threadIdx.x;

    if (b < 1024) {
        const float* src = (b < NBLK) ? rawU + (size_t)b * DDIM
                                      : rawV + (size_t)(b - NBLK) * DDIM;
        float* dst = (b < NBLK) ? unitU + (size_t)b * DDIM
                                : unitV + (size_t)(b - NBLK) * DDIM;
        float vals[4];
        float ss = 0.f;
#pragma unroll
        for (int i = 0; i < 4; i++) { vals[i] = src[t + i * 256]; ss += vals[i] * vals[i]; }
        __shared__ float red[4];
        ss = wave_reduce_sum(ss);
        if ((t & 63) == 0) red[t >> 6] = ss;
        __syncthreads();
        float tot = red[0] + red[1] + red[2] + red[3];
        float inv = 1.f / fmaxf(sqrtf(tot), 1e-6f);
#pragma unroll
        for (int i = 0; i < 4; i++) dst[t + i * 256] = vals[i] * inv;
    } else if (b < 9216) {
        int n = b - 1024;
        const float* row = x + (size_t)n * DDIM;
        float v[4];
        float s1 = 0.f, s2 = 0.f;
#pragma unroll
        for (int i = 0; i < 4; i++) {
            v[i] = row[t + i * 256];
            s1 += v[i];
            s2 += v[i] * v[i];
        }
        __shared__ float r1[4], r2[4];
        s1 = wave_reduce_sum(s1);
        s2 = wave_reduce_sum(s2);
        if ((t & 63) == 0) { r1[t >> 6] = s1; r2[t >> 6] = s2; }
        __syncthreads();
        float mu  = (r1[0] + r1[1] + r1[2] + r1[3]) * (1.f / DDIM);
        float var = (r2[0] + r2[1] + r2[2] + r2[3]) * (1.f / DDIM) - mu * mu;
        float rstd = rsqrtf(var + 1e-5f);
        __bf16* orow = lnb + (size_t)n * DDIM;
        __bf16* xrow = xb  + (size_t)n * DDIM;
#pragma unroll
        for (int i = 0; i < 4; i++) {
            int d = t + i * 256;
            orow[d] = (__bf16)((v[i] - mu) * rstd * ln_g[d] + ln_b[d]);
            xrow[d] = (__bf16)v[i];
        }
    } else if (b < 13312) {
        cast1024(W1, w1b, (size_t)(b - 9216) * 1024, t);
    } else if (b < 17408) {
        cast1024(W2, w2b, (size_t)(b - 13312) * 1024, t);
    } else {
        cast1024(router_W, rwb, (size_t)(b - 17408) * 1024, t);
    }
}

// ---------------------------------------------------------------------------
// Old-style 128xBN NT GEMM kept ONLY for the router (small: 8.6 GFLOP).
// MODE 0: D = fast_softplus(clip(acc+bias)) -> fp32
// ---------------------------------------------------------------------------
template <int MODE, int BN>
__global__ __launch_bounds__(256) void mfma_gemm(const __bf16* __restrict__ A,
                                                 const __bf16* __restrict__ B,
                                                 const float* __restrict__ bias,
                                                 void* __restrict__ Cv,
                                                 int M, int Nn, int Kk) {
    constexpr int NJ  = BN / 32;    // j-tiles per wave
    constexpr int NQB = BN / 64;    // B staging chunks per thread
    __shared__ __align__(16) __bf16 As[2][128 * 32];
    __shared__ __align__(16) __bf16 Bs[2][BN * 32];

    const int t    = threadIdx.x;
    const int lane = t & 63;
    const int wave = t >> 6;
    const int wm   = wave >> 1, wn = wave & 1;
    const int lr   = lane & 15, quad = lane >> 4;
    const int m0   = blockIdx.x * 128;
    const int n0   = blockIdx.y * BN;

    const int ca0 = t & 3;
    const __bf16* Ag[2];
    const __bf16* Bg[NQB];
    int ldsOffA[2], ldsOffB[NQB];
#pragma unroll
    for (int q = 0; q < 2; q++) {
        int idx = q * 256 + t;
        Ag[q]      = A + (size_t)(m0 + (idx >> 2)) * Kk + ca0 * 8;
        ldsOffA[q] = idx * 8;
    }
#pragma unroll
    for (int q = 0; q < NQB; q++) {
        int idx = q * 256 + t;
        Bg[q]      = B + (size_t)(n0 + (idx >> 2)) * Kk + ca0 * 8;
        ldsOffB[q] = idx * 8;
    }

    int raOff[4], rbOff[NJ];
#pragma unroll
    for (int i = 0; i < 4; i++)
        raOff[i] = (wm * 64 + i * 16 + lr) * 32 + quad * 8;
#pragma unroll
    for (int j = 0; j < NJ; j++)
        rbOff[j] = (wn * (BN / 2) + j * 16 + lr) * 32 + quad * 8;

    floatx4 acc[4][NJ];
#pragma unroll
    for (int i = 0; i < 4; i++)
#pragma unroll
        for (int j = 0; j < NJ; j++) acc[i][j] = (floatx4)0.f;

#pragma unroll
    for (int q = 0; q < 2; q++)   gload_lds16(Ag[q], &As[0][ldsOffA[q]]);
#pragma unroll
    for (int q = 0; q < NQB; q++) gload_lds16(Bg[q], &Bs[0][ldsOffB[q]]);

    const int niter = Kk >> 5;
    for (int it = 0; it < niter; ++it) {
        const int cur = it & 1;
        __syncthreads();
        if (it + 1 < niter) {
            const int nk = (it + 1) << 5;
            const int nb = cur ^ 1;
#pragma unroll
            for (int q = 0; q < 2; q++)   gload_lds16(Ag[q] + nk, &As[nb][ldsOffA[q]]);
#pragma unroll
            for (int q = 0; q < NQB; q++) gload_lds16(Bg[q] + nk, &Bs[nb][ldsOffB[q]]);
        }
        bf16x8 af[4], bfr[NJ];
#pragma unroll
        for (int i = 0; i < 4; i++)  af[i]  = *(const bf16x8*)&As[cur][raOff[i]];
#pragma unroll
        for (int j = 0; j < NJ; j++) bfr[j] = *(const bf16x8*)&Bs[cur][rbOff[j]];
#pragma unroll
        for (int i = 0; i < 4; i++)
#pragma unroll
            for (int j = 0; j < NJ; j++)
                acc[i][j] = __builtin_amdgcn_mfma_f32_16x16x32_bf16(af[i], bfr[j],
                                                                    acc[i][j], 0, 0, 0);
    }

    const int mBase = m0 + wm * 64 + quad * 4;
    const int nBase = n0 + wn * (BN / 2) + lr;
#pragma unroll
    for (int i = 0; i < 4; i++) {
#pragma unroll
        for (int j = 0; j < NJ; j++) {
            int n = nBase + j * 16;
#pragma unroll
            for (int r = 0; r < 4; r++) {
                int m = mBase + i * 16 + r;
                float v = acc[i][j][r];
                if (MODE == 0) {
                    float rr = v + bias[n];
                    rr = fminf(fmaxf(rr, -10.f), 10.f);
                    ((float*)Cv)[(size_t)m * Nn + n] = fast_softplus(rr);
                } else if (MODE == 1) {
                    ((__bf16*)Cv)[(size_t)m * Nn + n] = (__bf16)fast_gelu(v);
                } else {
                    ((float*)Cv)[(size_t)m * Nn + n] += v;
                }
            }
        }
    }
}

// ---------------------------------------------------------------------------
// 8-phase 256xBN NT GEMM (T1+T2+T3+T4+T5 port of the 256^2 template).
// BM=256, BK=64, 512 threads = 8 waves (2M x 4N). Per-wave tile 128 x BN/4,
// strip-interleaved: M strips {mh*128 + wm*64}, N strips {nh*(BN/2) + wn*(BN/8)}
// so each phase (mh,nh) consumes exactly one A-half and one B-half, making
// the 4-phase-ahead half-tile staging + counted vmcnt sufficient.
//   phase: ds_read subtile | stage 1 half-tile | vmcnt(VM) | s_barrier |
//          lgkmcnt(0) | setprio(1) 16(or 8) MFMA setprio(0) | s_barrier
// LDS XOR swizzle: col_byte ^= (row&7)<<4, applied on the READ address and
// inverse-applied on the per-lane GLOBAL source (global_load_lds writes
// linearly; rule: linear dest + inv-swz source + swz read).
// Stage order per tile == consumption order [Ah0,Bh0,Ah1,Bh1]; vmcnt(VM)
// each phase leaves exactly the last-2-phases' calls in flight (never 0).
// MODE 1: D = gelu(acc) -> bf16.  MODE 2: C += acc (fp32, tile-exclusive).
// ---------------------------------------------------------------------------
template <int MODE, int BN>
__global__ __launch_bounds__(512, 2) void mfma_gemm8(const __bf16* __restrict__ A,
                                                     const __bf16* __restrict__ B,
                                                     void* __restrict__ Cv,
                                                     int M, int Nn, int Kk) {
    constexpr int NJH    = BN / 128;   // n-frags per strip per wave (2 or 1)
    constexpr int NJ     = 2 * NJH;    // total n-frags per wave
    constexpr int BCALLS = BN / 128;   // gload calls per B half-tile per thread

    __shared__ __align__(16) __bf16 As[2][256 * 64];
    __shared__ __align__(16) __bf16 Bs[2][BN * 64];

    const int t    = threadIdx.x;
    const int lane = t & 63;
    const int wave = t >> 6;
    const int wm   = wave >> 2;        // 0..1
    const int wn   = wave & 3;         // 0..3
    const int lr   = lane & 15, quad = lane >> 4;

    // bijective XCD swizzle (gridDim.x % 8 == 0 guaranteed by launcher)
    const int nbn   = Nn / BN;
    const int chunk = gridDim.x >> 3;
    const int bid   = blockIdx.x;
    const int wg    = (bid & 7) * chunk + (bid >> 3);
    const int m0    = (wg / nbn) * 256;
    const int n0    = (wg % nbn) * BN;

    // ---- staging addresses: linear LDS dest, inverse-swizzled global src ----
    const __bf16* aSrc[2][2]; int aDst[2][2];      // [q][mh]
#pragma unroll
    for (int q = 0; q < 2; q++) {
        int idx = q * 512 + t;
        int row = idx >> 3;                         // 0..127 within half
        int cb  = ((idx & 7) << 4) ^ ((row & 7) << 4);  // swizzled src col (bytes)
#pragma unroll
        for (int mh = 0; mh < 2; mh++) {
            aSrc[q][mh] = A + (size_t)(m0 + mh * 128 + row) * Kk + (cb >> 1);
            aDst[q][mh] = (mh * 128 + row) * 64 + (idx & 7) * 8;
        }
    }
    const __bf16* bSrc[BCALLS][2]; int bDst[BCALLS][2];  // [q][nh]
#pragma unroll
    for (int q = 0; q < BCALLS; q++) {
        int idx = q * 512 + t;
        int row = idx >> 3;                         // 0..BN/2-1 within half
        int cb  = ((idx & 7) << 4) ^ ((row & 7) << 4);
#pragma unroll
        for (int nh = 0; nh < 2; nh++) {
            bSrc[q][nh] = B + (size_t)(n0 + nh * (BN / 2) + row) * Kk + (cb >> 1);
            bDst[q][nh] = (nh * (BN / 2) + row) * 64 + (idx & 7) * 8;
        }
    }

    // ---- ds-read per-lane offsets (elements), swizzled ----
    int aRd[2], bRd[2];
#pragma unroll
    for (int ks = 0; ks < 2; ks++) {
        int sw = ((ks * 64 + quad * 16) ^ ((lr & 7) << 4)) >> 1;
        aRd[ks] = (wm * 64 + lr) * 64 + sw;
        bRd[ks] = (wn * (BN / 8) + lr) * 64 + sw;
    }

    floatx4 acc[8][NJ];
#pragma unroll
    for (int i = 0; i < 8; i++)
#pragma unroll
        for (int j = 0; j < NJ; j++) acc[i][j] = (floatx4)0.f;

    bf16x8 af[4][2];       // A-frags for current m-strip [ii][ks]
    bf16x8 bfr[NJH][2];    // B-frags for current n-strip [jj][ks]

#define STAGE_A(KT, MH, BUF)                                                     \
    _Pragma("unroll") for (int q = 0; q < 2; q++)                                \
        gload_lds16(aSrc[q][MH] + (size_t)(KT) * 64, &As[BUF][aDst[q][MH]])
#define STAGE_B(KT, NH, BUF)                                                     \
    _Pragma("unroll") for (int q = 0; q < BCALLS; q++)                           \
        gload_lds16(bSrc[q][NH] + (size_t)(KT) * 64, &Bs[BUF][bDst[q][NH]])
#define LDA(MH)                                                                  \
    _Pragma("unroll") for (int ii = 0; ii < 4; ii++)                             \
    _Pragma("unroll") for (int ks = 0; ks < 2; ks++)                             \
        af[ii][ks] = *(const bf16x8*)&As[cur][aRd[ks] + (MH) * 8192 + ii * 1024]
#define LDB(NH)                                                                  \
    _Pragma("unroll") for (int jj = 0; jj < NJH; jj++)                           \
    _Pragma("unroll") for (int ks = 0; ks < 2; ks++)                             \
        bfr[jj][ks] = *(const bf16x8*)&Bs[cur][bRd[ks] + ((NH) * (BN / 2) + jj * 16) * 64]
#define MM(MH, NH)                                                               \
    _Pragma("unroll") for (int ii = 0; ii < 4; ii++)                             \
    _Pragma("unroll") for (int jj = 0; jj < NJH; jj++)                           \
    _Pragma("unroll") for (int ks = 0; ks < 2; ks++)                             \
        acc[(MH) * 4 + ii][(NH) * NJH + jj] =                                    \
            __builtin_amdgcn_mfma_f32_16x16x32_bf16(                             \
                af[ii][ks], bfr[jj][ks], acc[(MH) * 4 + ii][(NH) * NJH + jj],    \
                0, 0, 0)
#define WAITV()                                                                  \
    do { if constexpr (BCALLS == 2) asm volatile("s_waitcnt vmcnt(4)" ::: "memory"); \
         else                       asm volatile("s_waitcnt vmcnt(3)" ::: "memory"); } while (0)
#define WAITL() asm volatile("s_waitcnt lgkmcnt(0)" ::: "memory")
#define BARR()  __builtin_amdgcn_s_barrier()
#define PRIO1() __builtin_amdgcn_s_setprio(1)
#define PRIO0() __builtin_amdgcn_s_setprio(0)

    const int NT = Kk >> 6;

    // prologue: stage tile 0 in consumption order; publish Ah0+Bh0
    STAGE_A(0, 0, 0);
    STAGE_B(0, 0, 0);
    STAGE_A(0, 1, 0);
    STAGE_B(0, 1, 0);
    WAITV();
    BARR();

    for (int kt = 0; kt < NT; ++kt) {
        const int cur = kt & 1;
        const int nxt = cur ^ 1;
        const bool st = (kt + 1 < NT);
        // phase 0: (m0, n0) — stage next Ah0
        LDA(0); LDB(0);
        if (st) STAGE_A(kt + 1, 0, nxt);
        WAITV(); BARR(); WAITL();
        PRIO1(); MM(0, 0); PRIO0();
        BARR();
        // phase 1: (m1, n0) — B held, stage next Bh0
        LDA(1);
        if (st) STAGE_B(kt + 1, 0, nxt);
        WAITV(); BARR(); WAITL();
        PRIO1(); MM(1, 0); PRIO0();
        BARR();
        // phase 2: (m1, n1) — A held, stage next Ah1
        LDB(1);
        if (st) STAGE_A(kt + 1, 1, nxt);
        WAITV(); BARR(); WAITL();
        PRIO1(); MM(1, 1); PRIO0();
        BARR();
        // phase 3: (m0, n1) — B held, stage next Bh1
        LDA(0);
        if (st) STAGE_B(kt + 1, 1, nxt);
        WAITV(); BARR(); WAITL();
        PRIO1(); MM(0, 1); PRIO0();
        BARR();
    }

#undef STAGE_A
#undef STAGE_B
#undef LDA
#undef LDB
#undef MM
#undef WAITV
#undef WAITL
#undef BARR
#undef PRIO1
#undef PRIO0

    // ---- epilogue ----
#pragma unroll
    for (int i = 0; i < 8; i++) {
        const int mh = i >> 2, ii = i & 3;
#pragma unroll
        for (int j = 0; j < NJ; j++) {
            const int nh = j / NJH, jj = j % NJH;
            const int n = n0 + nh * (BN / 2) + wn * (BN / 8) + jj * 16 + lr;
#pragma unroll
            for (int r = 0; r < 4; r++) {
                const int m = m0 + mh * 128 + wm * 64 + ii * 16 + quad * 4 + r;
                const float v = acc[i][j][r];
                if (MODE == 1) {
                    ((__bf16*)Cv)[(size_t)m * Nn + n] = (__bf16)fast_gelu(v);
                } else {
                    ((float*)Cv)[(size_t)m * Nn + n] += v;
                }
            }
        }
    }
}

// ---------------------------------------------------------------------------
// Fused top-8 + dynamic path: one block (256 thr) per token.
// ---------------------------------------------------------------------------
__global__ __launch_bounds__(256) void topk_dyn_kernel(
        const float* __restrict__ alpha,
        const float* __restrict__ x,
        const float* __restrict__ unitU,
        const float* __restrict__ unitV,
        const float* __restrict__ gamma,
        float* __restrict__ out) {
    int n = blockIdx.x;
    int t = threadIdx.x;
    int lane = t & 63, wid = t >> 6;

    __shared__ int   sidx[8];
    __shared__ float shz[8];
    __shared__ float red[8][4];
    __shared__ float hz[8];

    if (wid == 0) {
        const float* row = alpha + (size_t)n * NBLK;
        float v[8];
#pragma unroll
        for (int i = 0; i < 8; i++) v[i] = row[lane + i * 64];
        float topv[8];
        int   topi[8];
        for (int s = 0; s < 8; s++) {
            float bv = v[0]; int bi = 0;
#pragma unroll
            for (int i = 1; i < 8; i++)
                if (v[i] > bv) { bv = v[i]; bi = i; }
            int gidx = lane + bi * 64;
#pragma unroll
            for (int off = 1; off < 64; off <<= 1) {
                float ov = __shfl_xor(bv, off, 64);
                int   oi = __shfl_xor(gidx, off, 64);
                if (ov > bv || (ov == bv && oi < gidx)) { bv = ov; gidx = oi; }
            }
            topv[s] = bv; topi[s] = gidx;
            if ((gidx & 63) == lane) v[gidx >> 6] = -1e30f;
        }
        float S = 0.f;
#pragma unroll
        for (int s = 0; s < 8; s++) S += topv[s];
        float zscale = tanhf(S) / (S + 1e-6f);
        if (lane < 8) {
            sidx[lane] = topi[lane];
            shz[lane]  = topv[lane] * zscale;
        }
    }
    __syncthreads();

    const float* xr = x + (size_t)n * DDIM;
    float xv[4];
#pragma unroll
    for (int i = 0; i < 4; i++) xv[i] = xr[t + i * 256];

    float acc[8];
#pragma unroll
    for (int k = 0; k < 8; k++) {
        const float* ur = unitU + (size_t)sidx[k] * DDIM;
        float a = 0.f;
#pragma unroll
        for (int i = 0; i < 4; i++) a = fmaf(xv[i], ur[t + i * 256], a);
        acc[k] = a;
    }
#pragma unroll
    for (int k = 0; k < 8; k++) {
        float a = wave_reduce_sum(acc[k]);
        if (lane == 0) red[k][wid] = a;
    }
    __syncthreads();
    if (t < 8) {
        float h = red[t][0] + red[t][1] + red[t][2] + red[t][3];
        hz[t] = h * shz[t];
    }
    __syncthreads();

    float* orow = out + (size_t)n * DDIM;
#pragma unroll
    for (int i = 0; i < 4; i++) {
        int d = t + i * 256;
        float s = 0.f;
#pragma unroll
        for (int k = 0; k < 8; k++)
            s = fmaf(hz[k], unitV[(size_t)sidx[k] * DDIM + d], s);
        orow[d] = s * gamma[d];
    }
}

// ---------------------------------------------------------------------------
extern "C" void kernel_launch(void* const* d_in, const int* in_sizes, int n_in,
                              void* d_out, int out_size, void* d_ws, size_t ws_size,
                              hipStream_t stream) {
    const float* x        = (const float*)d_in[0];
    const float* W1       = (const float*)d_in[1];
    const float* W2       = (const float*)d_in[2];
    const float* ln_g     = (const float*)d_in[3];
    const float* ln_b     = (const float*)d_in[4];
    const float* router_W = (const float*)d_in[5];
    const float* router_b = (const float*)d_in[6];
    const float* raw_U    = (const float*)d_in[7];
    const float* raw_V    = (const float*)d_in[8];
    const float* gamma    = (const float*)d_in[9];
    float* out = (float*)d_out;

    char* ws = (char*)d_ws;
    __bf16* lnb   = (__bf16*)(ws);                 // 16,777,216 B
    float*  alpha = (float*)(ws + 16777216u);      // 16,777,216 B
    __bf16* g1    = (__bf16*)(ws);                 // 67,108,864 B (after topk_dyn)
    __bf16* xb    = (__bf16*)(ws + 67108864u);     // 16,777,216 B
    __bf16* w1b   = (__bf16*)(ws + 83886080u);     //  8,388,608 B
    __bf16* w2b   = (__bf16*)(ws + 92274688u);     //  8,388,608 B
    __bf16* rwb   = (__bf16*)(ws + 100663296u);    //  1,048,576 B
    float*  unitU = (float*)(ws + 101711872u);     //  2,097,152 B
    float*  unitV = (float*)(ws + 103809024u);     //  2,097,152 B

    prep_kernel<<<17920, 256, 0, stream>>>(x, ln_g, ln_b, W1, W2, router_W,
                                           raw_U, raw_V, xb, lnb, w1b, w2b, rwb,
                                           unitU, unitV);

    // router: [8192,512] = lnb @ rwb^T, softplus epilogue. BN=64 -> 512 blocks.
    dim3 gR(N_TOK / 128, NBLK / 64);
    mfma_gemm<0, 64><<<gR, 256, 0, stream>>>(lnb, rwb, router_b, (void*)alpha,
                                             N_TOK, NBLK, DDIM);

    // fused top-8 + dynamic path (overwrites out)
    topk_dyn_kernel<<<N_TOK, 256, 0, stream>>>(alpha, x, unitU, unitV, gamma, out);

    // gemm1: g1 = gelu(x @ W1^T) -> bf16. 8-phase 256x256 tile, 512 blocks.
    mfma_gemm8<1, 256><<<dim3(512), dim3(512), 0, stream>>>(xb, w1b, (void*)g1,
                                                            N_TOK, HDIM, DDIM);

    // gemm2: out += g1 @ W2^T. 8-phase 256x128 tile -> 256 blocks (full GPU).
    mfma_gemm8<2, 128><<<dim3(256), dim3(512), 0, stream>>>(g1, w2b, (void*)out,
                                                            N_TOK, DDIM, HDIM);
}

// Round 3
// 363.964 us; speedup vs baseline: 1.0392x; 1.0338x over previous
//
#include <hip/hip_runtime.h>
#include <hip/hip_bf16.h>
#include <math.h>

#define N_TOK 8192
#define DDIM  1024
#define HDIM  4096
#define NBLK  512

typedef __bf16 bf16x8 __attribute__((ext_vector_type(8)));
typedef __bf16 bf16x4 __attribute__((ext_vector_type(4)));
typedef float  floatx4 __attribute__((ext_vector_type(4)));

__device__ __forceinline__ float wave_reduce_sum(float v) {
#pragma unroll
    for (int off = 32; off > 0; off >>= 1) v += __shfl_down(v, off, 64);
    return v;
}

__device__ __forceinline__ void gload_lds16(const void* g, void* l) {
    __builtin_amdgcn_global_load_lds((const __attribute__((address_space(1))) void*)g,
                                     (__attribute__((address_space(3))) void*)l,
                                     16, 0, 0);
}

// Branchless gelu via A&S 7.1.26 erf (max err 1.5e-7), ~13 VALU ops.
__device__ __forceinline__ float fast_gelu(float x) {
    float ax = fabsf(x);
    float z  = ax * 0.70710678118654752f;
    float t  = __builtin_amdgcn_rcpf(fmaf(0.3275911f, z, 1.0f));
    float p  = fmaf(fmaf(fmaf(fmaf(1.061405429f, t, -1.453152027f),
                              t, 1.421413741f),
                         t, -0.284496736f),
                    t, 0.254829592f);
    p *= t;
    float e = __expf(-z * z);
    float E = fmaf(-p, e, 1.0f);
    return 0.5f * fmaf(ax, E, x);
}

__device__ __forceinline__ float fast_softplus(float r) {
    return __logf(fmaf(1.0f, __expf(r), 1.0f));
}

// ---------------------------------------------------------------------------
// Fused prep kernel: unit rows / LN+x-cast / W casts
// ---------------------------------------------------------------------------
__device__ __forceinline__ void cast1024(const float* __restrict__ s,
                                         __bf16* __restrict__ d,
                                         size_t off, int t) {
    float4 v = ((const float4*)(s + off))[t];
    bf16x4 o;
    o.x = (__bf16)v.x; o.y = (__bf16)v.y;
    o.z = (__bf16)v.z; o.w = (__bf16)v.w;
    ((bf16x4*)(d + off))[t] = o;
}

__global__ __launch_bounds__(256) void prep_kernel(
        const float* __restrict__ x,
        const float* __restrict__ ln_g, const float* __restrict__ ln_b,
        const float* __restrict__ W1,   const float* __restrict__ W2,
        const float* __restrict__ router_W,
        const float* __restrict__ rawU, const float* __restrict__ rawV,
        __bf16* __restrict__ xb,  __bf16* __restrict__ lnb,
        __bf16* __restrict__ w1b, __bf16* __restrict__ w2b,
        __bf16* __restrict__ rwb,
        float* __restrict__ unitU, float* __restrict__ unitV) {
    int b = blockIdx.x;
    int t = threadIdx.x;

    if (b < 1024) {
        const float* src = (b < NBLK) ? rawU + (size_t)b * DDIM
                                      : rawV + (size_t)(b - NBLK) * DDIM;
        float* dst = (b < NBLK) ? unitU + (size_t)b * DDIM
                                : unitV + (size_t)(b - NBLK) * DDIM;
        float vals[4];
        float ss = 0.f;
#pragma unroll
        for (int i = 0; i < 4; i++) { vals[i] = src[t + i * 256]; ss += vals[i] * vals[i]; }
        __shared__ float red[4];
        ss = wave_reduce_sum(ss);
        if ((t & 63) == 0) red[t >> 6] = ss;
        __syncthreads();
        float tot = red[0] + red[1] + red[2] + red[3];
        float inv = 1.f / fmaxf(sqrtf(tot), 1e-6f);
#pragma unroll
        for (int i = 0; i < 4; i++) dst[t + i * 256] = vals[i] * inv;
    } else if (b < 9216) {
        int n = b - 1024;
        const float* row = x + (size_t)n * DDIM;
        float v[4];
        float s1 = 0.f, s2 = 0.f;
#pragma unroll
        for (int i = 0; i < 4; i++) {
            v[i] = row[t + i * 256];
            s1 += v[i];
            s2 += v[i] * v[i];
        }
        __shared__ float r1[4], r2[4];
        s1 = wave_reduce_sum(s1);
        s2 = wave_reduce_sum(s2);
        if ((t & 63) == 0) { r1[t >> 6] = s1; r2[t >> 6] = s2; }
        __syncthreads();
        float mu  = (r1[0] + r1[1] + r1[2] + r1[3]) * (1.f / DDIM);
        float var = (r2[0] + r2[1] + r2[2] + r2[3]) * (1.f / DDIM) - mu * mu;
        float rstd = rsqrtf(var + 1e-5f);
        __bf16* orow = lnb + (size_t)n * DDIM;
        __bf16* xrow = xb  + (size_t)n * DDIM;
#pragma unroll
        for (int i = 0; i < 4; i++) {
            int d = t + i * 256;
            orow[d] = (__bf16)((v[i] - mu) * rstd * ln_g[d] + ln_b[d]);
            xrow[d] = (__bf16)v[i];
        }
    } else if (b < 13312) {
        cast1024(W1, w1b, (size_t)(b - 9216) * 1024, t);
    } else if (b < 17408) {
        cast1024(W2, w2b, (size_t)(b - 13312) * 1024, t);
    } else {
        cast1024(router_W, rwb, (size_t)(b - 17408) * 1024, t);
    }
}

// ---------------------------------------------------------------------------
// Old-style 128xBN NT GEMM kept ONLY for the router (small: 8.6 GFLOP).
// MODE 0: D = fast_softplus(clip(acc+bias)) -> fp32
// ---------------------------------------------------------------------------
template <int MODE, int BN>
__global__ __launch_bounds__(256) void mfma_gemm(const __bf16* __restrict__ A,
                                                 const __bf16* __restrict__ B,
                                                 const float* __restrict__ bias,
                                                 void* __restrict__ Cv,
                                                 int M, int Nn, int Kk) {
    constexpr int NJ  = BN / 32;
    constexpr int NQB = BN / 64;
    __shared__ __align__(16) __bf16 As[2][128 * 32];
    __shared__ __align__(16) __bf16 Bs[2][BN * 32];

    const int t    = threadIdx.x;
    const int lane = t & 63;
    const int wave = t >> 6;
    const int wm   = wave >> 1, wn = wave & 1;
    const int lr   = lane & 15, quad = lane >> 4;
    const int m0   = blockIdx.x * 128;
    const int n0   = blockIdx.y * BN;

    const int ca0 = t & 3;
    const __bf16* Ag[2];
    const __bf16* Bg[NQB];
    int ldsOffA[2], ldsOffB[NQB];
#pragma unroll
    for (int q = 0; q < 2; q++) {
        int idx = q * 256 + t;
        Ag[q]      = A + (size_t)(m0 + (idx >> 2)) * Kk + ca0 * 8;
        ldsOffA[q] = idx * 8;
    }
#pragma unroll
    for (int q = 0; q < NQB; q++) {
        int idx = q * 256 + t;
        Bg[q]      = B + (size_t)(n0 + (idx >> 2)) * Kk + ca0 * 8;
        ldsOffB[q] = idx * 8;
    }

    int raOff[4], rbOff[NJ];
#pragma unroll
    for (int i = 0; i < 4; i++)
        raOff[i] = (wm * 64 + i * 16 + lr) * 32 + quad * 8;
#pragma unroll
    for (int j = 0; j < NJ; j++)
        rbOff[j] = (wn * (BN / 2) + j * 16 + lr) * 32 + quad * 8;

    floatx4 acc[4][NJ];
#pragma unroll
    for (int i = 0; i < 4; i++)
#pragma unroll
        for (int j = 0; j < NJ; j++) acc[i][j] = (floatx4)0.f;

#pragma unroll
    for (int q = 0; q < 2; q++)   gload_lds16(Ag[q], &As[0][ldsOffA[q]]);
#pragma unroll
    for (int q = 0; q < NQB; q++) gload_lds16(Bg[q], &Bs[0][ldsOffB[q]]);

    const int niter = Kk >> 5;
    for (int it = 0; it < niter; ++it) {
        const int cur = it & 1;
        __syncthreads();
        if (it + 1 < niter) {
            const int nk = (it + 1) << 5;
            const int nb = cur ^ 1;
#pragma unroll
            for (int q = 0; q < 2; q++)   gload_lds16(Ag[q] + nk, &As[nb][ldsOffA[q]]);
#pragma unroll
            for (int q = 0; q < NQB; q++) gload_lds16(Bg[q] + nk, &Bs[nb][ldsOffB[q]]);
        }
        bf16x8 af[4], bfr[NJ];
#pragma unroll
        for (int i = 0; i < 4; i++)  af[i]  = *(const bf16x8*)&As[cur][raOff[i]];
#pragma unroll
        for (int j = 0; j < NJ; j++) bfr[j] = *(const bf16x8*)&Bs[cur][rbOff[j]];
#pragma unroll
        for (int i = 0; i < 4; i++)
#pragma unroll
            for (int j = 0; j < NJ; j++)
                acc[i][j] = __builtin_amdgcn_mfma_f32_16x16x32_bf16(af[i], bfr[j],
                                                                    acc[i][j], 0, 0, 0);
    }

    const int mBase = m0 + wm * 64 + quad * 4;
    const int nBase = n0 + wn * (BN / 2) + lr;
#pragma unroll
    for (int i = 0; i < 4; i++) {
#pragma unroll
        for (int j = 0; j < NJ; j++) {
            int n = nBase + j * 16;
#pragma unroll
            for (int r = 0; r < 4; r++) {
                int m = mBase + i * 16 + r;
                float v = acc[i][j][r];
                if (MODE == 0) {
                    float rr = v + bias[n];
                    rr = fminf(fmaxf(rr, -10.f), 10.f);
                    ((float*)Cv)[(size_t)m * Nn + n] = fast_softplus(rr);
                } else if (MODE == 1) {
                    ((__bf16*)Cv)[(size_t)m * Nn + n] = (__bf16)fast_gelu(v);
                } else {
                    ((float*)Cv)[(size_t)m * Nn + n] += v;
                }
            }
        }
    }
}

// ---------------------------------------------------------------------------
// 256x256 8-phase NT GEMM, BK=64, 512 thr = 8 waves (2M x 4N), wave 128x64.
// Register-holding snake per K-tile: P0 MM(0,0)[LDA0+LDB0, 12 rd],
// P1 MM(0,1)[LDB1, 4 rd], P2 MM(1,1)[LDA1, 8 rd], P3 MM(1,0)[0 rd]
// => 24 ds_read_b128 per 64 MFMA per wave (m201 parity; round-1 BN=128 was
// 28 rd / 32 MFMA => 23% LDS-read cap, matched measured 24.4% MfmaUtil).
// Staging: 1 half-tile/phase, 6-7 phases ahead of first use; prologue = 7
// half-tiles; counted vmcnt(10) at P0/P1/P3 (none at P2), tail-peeled exact
// counts for the last 2 K-tiles. LDS XOR swizzle as round 1 (0 conflicts).
// MODE 1: D = gelu(acc)->bf16.  MODE 2: atomicAdd fp32 (split-K safe).
// ---------------------------------------------------------------------------
template <int MODE, int SPLITK>
__global__ __launch_bounds__(512, 2) void mfma_gemm8v2(const __bf16* __restrict__ A,
                                                       const __bf16* __restrict__ B,
                                                       void* __restrict__ Cv,
                                                       int M, int Nn, int Kk) {
    __shared__ __align__(16) __bf16 As[2][256 * 64];
    __shared__ __align__(16) __bf16 Bs[2][256 * 64];

    const int t    = threadIdx.x;
    const int lane = t & 63;
    const int wave = t >> 6;
    const int wm   = wave >> 2;        // 0..1
    const int wn   = wave & 3;         // 0..3
    const int lr   = lane & 15, quad = lane >> 4;

    // bijective XCD swizzle (gridDim.x % 8 == 0 by construction)
    const int nbn   = Nn >> 8;
    const int nmb   = M >> 8;
    const int chunk = gridDim.x >> 3;
    const int bid   = blockIdx.x;
    const int wg    = (bid & 7) * chunk + (bid >> 3);
    const int kslc  = wg / (nmb * nbn);
    const int rem   = wg % (nmb * nbn);
    const int m0    = (rem / nbn) * 256;
    const int n0    = (rem % nbn) * 256;
    const int kseg  = Kk / SPLITK;
    const int NT    = kseg >> 6;

    // ---- staging: linear LDS dest, inverse-swizzled global source ----
    const int srow = t >> 3;                               // 0..63
    const int scb  = ((t & 7) << 4) ^ ((srow & 7) << 4);   // swizzled byte col
    const __bf16* aP = A + (size_t)(m0 + srow) * Kk + (size_t)kslc * kseg + (scb >> 1);
    const __bf16* bP = B + (size_t)(n0 + srow) * Kk + (size_t)kslc * kseg + (scb >> 1);
    const int dP = srow * 64 + (t & 7) * 8;                // elems

    // ---- ds-read per-lane offsets (elements), swizzled ----
    int aRd[2], bRd[2];
#pragma unroll
    for (int ks = 0; ks < 2; ks++) {
        int sw = ((ks * 64 + quad * 16) ^ ((lr & 7) << 4)) >> 1;
        aRd[ks] = (wm * 64 + lr) * 64 + sw;
        bRd[ks] = (wn * 32 + lr) * 64 + sw;
    }

    floatx4 acc[8][4];
#pragma unroll
    for (int i = 0; i < 8; i++)
#pragma unroll
        for (int j = 0; j < 4; j++) acc[i][j] = (floatx4)0.f;

    bf16x8 af[4][2];        // A frags, current m-strip
    bf16x8 bfr0[2][2];      // B frags, n-strip 0 (held across tile)
    bf16x8 bfr1[2][2];      // B frags, n-strip 1

#define STAGE_A(KT, MH, BUF)                                                        \
    _Pragma("unroll") for (int q = 0; q < 2; q++)                                   \
        gload_lds16(aP + (size_t)(KT) * 64 + (size_t)(q * 64 + (MH) * 128) * Kk,    \
                    &As[BUF][dP + (q * 64 + (MH) * 128) * 64])
#define STAGE_B(KT, NH, BUF)                                                        \
    _Pragma("unroll") for (int q = 0; q < 2; q++)                                   \
        gload_lds16(bP + (size_t)(KT) * 64 + (size_t)(q * 64 + (NH) * 128) * Kk,    \
                    &Bs[BUF][dP + (q * 64 + (NH) * 128) * 64])
#define LDA(CUR, MH)                                                                \
    _Pragma("unroll") for (int ii = 0; ii < 4; ii++)                                \
    _Pragma("unroll") for (int ks = 0; ks < 2; ks++)                                \
        af[ii][ks] = *(const bf16x8*)&As[CUR][aRd[ks] + (MH) * 8192 + ii * 1024]
#define LDB(CUR, NH, DST)                                                           \
    _Pragma("unroll") for (int jj = 0; jj < 2; jj++)                                \
    _Pragma("unroll") for (int ks = 0; ks < 2; ks++)                                \
        DST[jj][ks] = *(const bf16x8*)&Bs[CUR][bRd[ks] + ((NH) * 128 + jj * 16) * 64]
#define MM(MH, NH, BFR)                                                             \
    _Pragma("unroll") for (int ii = 0; ii < 4; ii++)                                \
    _Pragma("unroll") for (int jj = 0; jj < 2; jj++)                                \
    _Pragma("unroll") for (int ks = 0; ks < 2; ks++)                                \
        acc[(MH) * 4 + ii][(NH) * 2 + jj] =                                         \
            __builtin_amdgcn_mfma_f32_16x16x32_bf16(                                \
                af[ii][ks], BFR[jj][ks], acc[(MH) * 4 + ii][(NH) * 2 + jj], 0, 0, 0)
#define VWAIT(NSTR) asm volatile("s_waitcnt vmcnt(" NSTR ")" ::: "memory")
#define WAITL()     asm volatile("s_waitcnt lgkmcnt(0)" ::: "memory")
#define BARR()      __builtin_amdgcn_s_barrier()
#define PRIO1()     __builtin_amdgcn_s_setprio(1)
#define PRIO0()     __builtin_amdgcn_s_setprio(0)

// One K-tile: ST1 = stage A1[kt+1] at P0; ST2 = stage A0/B0/B1[kt+2] at P1-P3.
// VM0/VM1/VM3 = vmcnt literals at P0/P1/P3 (wait covers the NEXT phase's reads;
// P2 needs none since P3 reads nothing).
#define TILE(KT, CUR, ST1, ST2, VM0, VM1, VM3)                                      \
    do {                                                                            \
        LDA(CUR, 0); LDB(CUR, 0, bfr0);                                             \
        if (ST1) { STAGE_A((KT) + 1, 1, ((KT) + 1) & 1); }                          \
        VWAIT(VM0); BARR(); WAITL();                                                \
        PRIO1(); MM(0, 0, bfr0); PRIO0(); BARR();                                   \
        LDB(CUR, 1, bfr1);                                                          \
        if (ST2) { STAGE_A((KT) + 2, 0, (KT) & 1); }                                \
        VWAIT(VM1); BARR(); WAITL();                                                \
        PRIO1(); MM(0, 1, bfr1); PRIO0(); BARR();                                   \
        LDA(CUR, 1);                                                                \
        if (ST2) { STAGE_B((KT) + 2, 0, (KT) & 1); }                                \
        BARR(); WAITL();                                                            \
        PRIO1(); MM(1, 1, bfr1); PRIO0(); BARR();                                   \
        if (ST2) { STAGE_B((KT) + 2, 1, (KT) & 1); }                                \
        VWAIT(VM3); BARR();                                                         \
        PRIO1(); MM(1, 0, bfr0); PRIO0(); BARR();                                   \
    } while (0)

    // prologue: 7 half-tiles in consumption order [A0 B0 B1 A1]_t0 [A0 B0 B1]_t1
    STAGE_A(0, 0, 0); STAGE_B(0, 0, 0); STAGE_B(0, 1, 0); STAGE_A(0, 1, 0);
    STAGE_A(1, 0, 1); STAGE_B(1, 0, 1); STAGE_B(1, 1, 1);
    VWAIT("10");            // 14 calls out -> oldest 4 (A0,B0 of tile 0) done
    BARR();

    for (int kt = 0; kt < NT - 2; ++kt)
        TILE(kt, kt & 1, true, true, "10", "10", "10");
    TILE(NT - 2, (NT - 2) & 1, true, false, "10", "8", "4");
    TILE(NT - 1, (NT - 1) & 1, false, false, "2", "0", "0");

#undef STAGE_A
#undef STAGE_B
#undef LDA
#undef LDB
#undef MM
#undef VWAIT
#undef WAITL
#undef BARR
#undef PRIO1
#undef PRIO0
#undef TILE

    // ---- epilogue ----
#pragma unroll
    for (int i = 0; i < 8; i++) {
        const int mh = i >> 2, ii = i & 3;
#pragma unroll
        for (int j = 0; j < 4; j++) {
            const int nh = j >> 1, jj = j & 1;
            const int n = n0 + nh * 128 + wn * 32 + jj * 16 + lr;
#pragma unroll
            for (int r = 0; r < 4; r++) {
                const int m = m0 + mh * 128 + wm * 64 + ii * 16 + quad * 4 + r;
                const float v = acc[i][j][r];
                if (MODE == 1) {
                    ((__bf16*)Cv)[(size_t)m * Nn + n] = (__bf16)fast_gelu(v);
                } else {
                    atomicAdd(&((float*)Cv)[(size_t)m * Nn + n], v);
                }
            }
        }
    }
}

// ---------------------------------------------------------------------------
// Fused top-8 + dynamic path: one block (256 thr) per token.
// ---------------------------------------------------------------------------
__global__ __launch_bounds__(256) void topk_dyn_kernel(
        const float* __restrict__ alpha,
        const float* __restrict__ x,
        const float* __restrict__ unitU,
        const float* __restrict__ unitV,
        const float* __restrict__ gamma,
        float* __restrict__ out) {
    int n = blockIdx.x;
    int t = threadIdx.x;
    int lane = t & 63, wid = t >> 6;

    __shared__ int   sidx[8];
    __shared__ float shz[8];
    __shared__ float red[8][4];
    __shared__ float hz[8];

    if (wid == 0) {
        const float* row = alpha + (size_t)n * NBLK;
        float v[8];
#pragma unroll
        for (int i = 0; i < 8; i++) v[i] = row[lane + i * 64];
        float topv[8];
        int   topi[8];
        for (int s = 0; s < 8; s++) {
            float bv = v[0]; int bi = 0;
#pragma unroll
            for (int i = 1; i < 8; i++)
                if (v[i] > bv) { bv = v[i]; bi = i; }
            int gidx = lane + bi * 64;
#pragma unroll
            for (int off = 1; off < 64; off <<= 1) {
                float ov = __shfl_xor(bv, off, 64);
                int   oi = __shfl_xor(gidx, off, 64);
                if (ov > bv || (ov == bv && oi < gidx)) { bv = ov; gidx = oi; }
            }
            topv[s] = bv; topi[s] = gidx;
            if ((gidx & 63) == lane) v[gidx >> 6] = -1e30f;
        }
        float S = 0.f;
#pragma unroll
        for (int s = 0; s < 8; s++) S += topv[s];
        float zscale = tanhf(S) / (S + 1e-6f);
        if (lane < 8) {
            sidx[lane] = topi[lane];
            shz[lane]  = topv[lane] * zscale;
        }
    }
    __syncthreads();

    const float* xr = x + (size_t)n * DDIM;
    float xv[4];
#pragma unroll
    for (int i = 0; i < 4; i++) xv[i] = xr[t + i * 256];

    float acc[8];
#pragma unroll
    for (int k = 0; k < 8; k++) {
        const float* ur = unitU + (size_t)sidx[k] * DDIM;
        float a = 0.f;
#pragma unroll
        for (int i = 0; i < 4; i++) a = fmaf(xv[i], ur[t + i * 256], a);
        acc[k] = a;
    }
#pragma unroll
    for (int k = 0; k < 8; k++) {
        float a = wave_reduce_sum(acc[k]);
        if (lane == 0) red[k][wid] = a;
    }
    __syncthreads();
    if (t < 8) {
        float h = red[t][0] + red[t][1] + red[t][2] + red[t][3];
        hz[t] = h * shz[t];
    }
    __syncthreads();

    float* orow = out + (size_t)n * DDIM;
#pragma unroll
    for (int i = 0; i < 4; i++) {
        int d = t + i * 256;
        float s = 0.f;
#pragma unroll
        for (int k = 0; k < 8; k++)
            s = fmaf(hz[k], unitV[(size_t)sidx[k] * DDIM + d], s);
        orow[d] = s * gamma[d];
    }
}

// ---------------------------------------------------------------------------
extern "C" void kernel_launch(void* const* d_in, const int* in_sizes, int n_in,
                              void* d_out, int out_size, void* d_ws, size_t ws_size,
                              hipStream_t stream) {
    const float* x        = (const float*)d_in[0];
    const float* W1       = (const float*)d_in[1];
    const float* W2       = (const float*)d_in[2];
    const float* ln_g     = (const float*)d_in[3];
    const float* ln_b     = (const float*)d_in[4];
    const float* router_W = (const float*)d_in[5];
    const float* router_b = (const float*)d_in[6];
    const float* raw_U    = (const float*)d_in[7];
    const float* raw_V    = (const float*)d_in[8];
    const float* gamma    = (const float*)d_in[9];
    float* out = (float*)d_out;

    char* ws = (char*)d_ws;
    __bf16* lnb   = (__bf16*)(ws);                 // 16,777,216 B
    float*  alpha = (float*)(ws + 16777216u);      // 16,777,216 B
    __bf16* g1    = (__bf16*)(ws);                 // 67,108,864 B (after topk_dyn)
    __bf16* xb    = (__bf16*)(ws + 67108864u);     // 16,777,216 B
    __bf16* w1b   = (__bf16*)(ws + 83886080u);     //  8,388,608 B
    __bf16* w2b   = (__bf16*)(ws + 92274688u);     //  8,388,608 B
    __bf16* rwb   = (__bf16*)(ws + 100663296u);    //  1,048,576 B
    float*  unitU = (float*)(ws + 101711872u);     //  2,097,152 B
    float*  unitV = (float*)(ws + 103809024u);     //  2,097,152 B

    prep_kernel<<<17920, 256, 0, stream>>>(x, ln_g, ln_b, W1, W2, router_W,
                                           raw_U, raw_V, xb, lnb, w1b, w2b, rwb,
                                           unitU, unitV);

    // router: [8192,512] = lnb @ rwb^T, softplus epilogue. BN=64 -> 512 blocks.
    dim3 gR(N_TOK / 128, NBLK / 64);
    mfma_gemm<0, 64><<<gR, 256, 0, stream>>>(lnb, rwb, router_b, (void*)alpha,
                                             N_TOK, NBLK, DDIM);

    // fused top-8 + dynamic path (overwrites out)
    topk_dyn_kernel<<<N_TOK, 256, 0, stream>>>(alpha, x, unitU, unitV, gamma, out);

    // gemm1: g1 = gelu(x @ W1^T) -> bf16. 256x256 tile, grid 32x16 = 512.
    mfma_gemm8v2<1, 1><<<dim3(512), dim3(512), 0, stream>>>(xb, w1b, (void*)g1,
                                                            N_TOK, HDIM, DDIM);

    // gemm2: out += g1 @ W2^T. 256x256 tile, split-K=2 -> 32x4x2 = 256 blocks
    // (full GPU); fp32 atomicAdd epilogue onto topk-prefilled out.
    mfma_gemm8v2<2, 2><<<dim3(256), dim3(512), 0, stream>>>(g1, w2b, (void*)out,
                                                            N_TOK, DDIM, HDIM);
}